// Round 6
// baseline (118.682 us; speedup 1.0000x reference)
//
#include <hip/hip_runtime.h>

// x: [B=16, T=16384, C=64] fp32. bp_sos/lp_sos: [2,6] fp32 rows (b0,b1,b2,a0,a1,a2; a0==1).
#define B_LEN 16
#define T_LEN 16384
#define C_LEN 64
#define CHUNK 64    // outputs per thread; amp 2.0x (warm 64) -- grid = 256 blocks = 1/CU
#define WARM  64    // zero-state warmup; transient ~0.83^64 ~ 7e-6 (empirically safe: absmax 0.0156)

// R11 = R10 with the compile fix: __builtin_nontemporal_store requires a clang
// vector type, not HIP's float4 class -> use ext_vector_type(4).
// R10 theory (untested due to compile error): R9 landed ~30us vs 21.3us floor,
// BW stuck at ~4.5 TB/s; every VMEM op was a 4B/lane dword (256B/wave) --
// instruction-granularity-limited MLP (violates G13's 16B/lane sweet spot).
// Each thread owns 4 CONTIGUOUS channels -> every load/store is dwordx4
// (16B/lane, 1KB/wave-inst), 4x fewer VMEM instructions, 4x bytes in flight.
// Block = 16 batches x 16 channel-quads = 256 thr; grid = T/64 = 256 = 1 block/CU
// (4 waves/CU, 1/SIMD): TLP low by design, hiding is the 16-sample register ring
// (~2000 issue-cy prefetch distance >> 900cy HBM). 4 independent IIR chains per
// thread widen FMA ILP. Per-channel arithmetic order unchanged -> absmax stays
// 0.015625 exactly.
typedef float f32x4 __attribute__((ext_vector_type(4)));

__global__ __launch_bounds__(256, 1) void iir_vec4_kernel(
    const float* __restrict__ x,
    const float* __restrict__ bp,
    const float* __restrict__ lp,
    float* __restrict__ out)
{
    const int cq    = threadIdx.x & 15;        // channel quad: channels 4cq..4cq+3
    const int b     = threadIdx.x >> 4;        // batch 0..15
    const int chunk = blockIdx.x;              // 0..T/CHUNK-1

    // Uniform coefficients -> scalar (SGPR) loads. a's negated so updates are pure FMA.
    const float b10 = bp[0], b11 = bp[1], b12 = bp[2],  a11 = -bp[4],  a12 = -bp[5];
    const float b20 = bp[6], b21 = bp[7], b22 = bp[8],  a21 = -bp[10], a22 = -bp[11];
    const float b30 = lp[0], b31 = lp[1], b32 = lp[2],  a31 = -lp[4],  a32 = -lp[5];
    const float b40 = lp[6], b41 = lp[7], b42 = lp[8],  a41 = -lp[10], a42 = -lp[11];

    const int t_out0 = chunk * CHUNK;
    const int warm   = (t_out0 < WARM) ? t_out0 : WARM;  // 0 (chunk 0) or 64, block-uniform
    const int t0     = t_out0 - warm;

    // DF2T state: 2 per section x 4 channels (all statically indexed after unroll)
    float s11[4] = {0,0,0,0}, s12[4] = {0,0,0,0};
    float s21[4] = {0,0,0,0}, s22[4] = {0,0,0,0};
    float s31[4] = {0,0,0,0}, s32[4] = {0,0,0,0};
    float s41[4] = {0,0,0,0}, s42[4] = {0,0,0,0};

    const float* __restrict__ lq = x   + ((size_t)b * T_LEN + t0)     * C_LEN + 4 * cq;
    float*       __restrict__ po = out + ((size_t)b * T_LEN + t_out0) * C_LEN + 4 * cq;

    // One sample, 4 channels. ch loop unrolled -> 4 interleaved dep chains.
    auto step4 = [&](const float* xn4, float* y4) {
#pragma unroll
        for (int ch = 0; ch < 4; ++ch) {
            float xn = xn4[ch];
            // section 1 (bandpass)
            float y1 = fmaf(b10, xn, s11[ch]);
            s11[ch] = fmaf(b11, xn, fmaf(a11, y1, s12[ch]));
            s12[ch] = fmaf(b12, xn, a12 * y1);
            // section 2 (bandpass)
            float y2 = fmaf(b20, y1, s21[ch]);
            s21[ch] = fmaf(b21, y1, fmaf(a21, y2, s22[ch]));
            s22[ch] = fmaf(b22, y1, a22 * y2);
            // squaring nonlinearity
            float v = y2 * y2;
            // section 3 (lowpass)
            float y3 = fmaf(b30, v, s31[ch]);
            s31[ch] = fmaf(b31, v, fmaf(a31, y3, s32[ch]));
            s32[ch] = fmaf(b32, v, a32 * y3);
            // section 4 (lowpass)
            float y4v = fmaf(b40, y3, s41[ch]);
            s41[ch] = fmaf(b41, y3, fmaf(a41, y4v, s42[ch]));
            s42[ch] = fmaf(b42, y3, a42 * y4v);
            y4[ch] = y4v;
        }
    };

    // 4-group register ring; each group = 4 samples x 4 channels = 16 floats (4 dwordx4).
    float P0[16], P1[16], P2[16], P3[16];

    auto load4 = [&](float* d) {            // 4 x global_load_dwordx4, imm offsets
#pragma unroll
        for (int j = 0; j < 4; ++j)
            *reinterpret_cast<f32x4*>(d + 4 * j) =
                *reinterpret_cast<const f32x4*>(lq + j * C_LEN);
        lq += 4 * C_LEN;
    };
    auto warm4 = [&](float* d) {
        float yt[4];
#pragma unroll
        for (int j = 0; j < 4; ++j) step4(d + 4 * j, yt);   // discard outputs
    };
    auto fence = [&]() { __builtin_amdgcn_sched_barrier(0); };

    // Emit phase: compute -> prefetch loads -> stores (stores LAST in vmcnt FIFO, R9).
    auto emit4_reload = [&](float* d) {
        float Y[16];
#pragma unroll
        for (int j = 0; j < 4; ++j) step4(d + 4 * j, Y + 4 * j);
        load4(d);          // overwrites d; per-reg anti-dep
        fence();           // stores must not be scheduled above the loads
#pragma unroll
        for (int j = 0; j < 4; ++j)
            __builtin_nontemporal_store(*reinterpret_cast<const f32x4*>(Y + 4 * j),
                                        reinterpret_cast<f32x4*>(po + j * C_LEN));
        po += 4 * C_LEN;
        fence();
    };
    auto emit4_final = [&](float* d) {
        float Y[16];
#pragma unroll
        for (int j = 0; j < 4; ++j) step4(d + 4 * j, Y + 4 * j);
#pragma unroll
        for (int j = 0; j < 4; ++j)
            __builtin_nontemporal_store(*reinterpret_cast<const f32x4*>(Y + 4 * j),
                                        reinterpret_cast<f32x4*>(po + j * C_LEN));
        po += 4 * C_LEN;
        fence();
    };

    // Prologue: 16 samples in flight before the first dependent FMA.
    load4(P0); load4(P1); load4(P2); load4(P3);
    fence();

    // Warm: warm/16 rotations (0 or 4). {consume 4 samples, reload 4}, fenced.
    const int nrot = warm >> 4;
#pragma unroll 1
    for (int r = 0; r < nrot; ++r) {
        warm4(P0); load4(P0); fence();
        warm4(P1); load4(P1); fence();
        warm4(P2); load4(P2); fence();
        warm4(P3); load4(P3); fence();
    }
    // Emit with reload: 3 rotations. Total loads = warm + CHUNK samples, ending
    // exactly at t_out0 + CHUNK <= T: no OOB.
#pragma unroll 1
    for (int r = 0; r < (CHUNK - 16) / 16; ++r) {
        emit4_reload(P0);
        emit4_reload(P1);
        emit4_reload(P2);
        emit4_reload(P3);
    }
    // Final 16 samples: no further loads.
    emit4_final(P0);
    emit4_final(P1);
    emit4_final(P2);
    emit4_final(P3);
}

extern "C" void kernel_launch(void* const* d_in, const int* in_sizes, int n_in,
                              void* d_out, int out_size, void* d_ws, size_t ws_size,
                              hipStream_t stream) {
    const float* x  = (const float*)d_in[0];
    const float* bp = (const float*)d_in[1];
    const float* lp = (const float*)d_in[2];
    float* out      = (float*)d_out;

    dim3 grid(T_LEN / CHUNK);   // 256 blocks -> 1 block/CU
    dim3 block(256);            // 16 batches x 16 channel-quads
    iir_vec4_kernel<<<grid, block, 0, stream>>>(x, bp, lp, out);
}